// Round 1
// baseline (806.568 us; speedup 1.0000x reference)
//
#include <hip/hip_runtime.h>
#include <hip/hip_bf16.h>

#define NN 100000
#define NE 3200000
#define IN_F 128
#define HID 32

typedef __hip_bfloat16 bf16;

// ---------------- CSR build ----------------

__global__ void k_init(float* __restrict__ deg, int* __restrict__ cnt) {
    int i = blockIdx.x * blockDim.x + threadIdx.x;
    if (i < NN) { deg[i] = 1.0f; cnt[i] = 0; }  // self-loop weight 1
}

__global__ void k_count(const int* __restrict__ ei, const float* __restrict__ ew,
                        float* __restrict__ deg, int* __restrict__ cnt) {
    int e = blockIdx.x * blockDim.x + threadIdx.x;
    if (e < NE) {
        int dst = ei[NE + e];
        atomicAdd(&cnt[dst], 1);
        atomicAdd(&deg[dst], ew[e]);
    }
}

// S1: per-1024-chunk sums
__global__ void k_blocksum(const int* __restrict__ cnt, int* __restrict__ partials) {
    __shared__ int lds[256];
    int t = threadIdx.x;
    int base = blockIdx.x * 1024 + t * 4;
    int s = 0;
#pragma unroll
    for (int j = 0; j < 4; j++) { int idx = base + j; if (idx < NN) s += cnt[idx]; }
    lds[t] = s; __syncthreads();
    for (int off = 128; off > 0; off >>= 1) {
        if (t < off) lds[t] += lds[t + off];
        __syncthreads();
    }
    if (t == 0) partials[blockIdx.x] = lds[0];
}

// S2: tiny serial exclusive scan of partials (98 entries)
__global__ void k_scanpartials(int* __restrict__ partials, int nb, int* __restrict__ rowstart) {
    if (threadIdx.x == 0 && blockIdx.x == 0) {
        int run = 0;
        for (int i = 0; i < nb; i++) { int v = partials[i]; partials[i] = run; run += v; }
        rowstart[NN] = run;  // == NE
    }
}

// S3: block-local exclusive scan -> rowstart/cursor; also deg -> dinv in place
__global__ void k_scatterscan(const int* __restrict__ cnt, const int* __restrict__ partials,
                              int* __restrict__ rowstart, int* __restrict__ cursor,
                              float* __restrict__ deg /* in: deg, out: dinv */) {
    __shared__ int lds[256];
    int t = threadIdx.x;
    int base = blockIdx.x * 1024 + t * 4;
    int v[4]; int s = 0;
#pragma unroll
    for (int j = 0; j < 4; j++) { int idx = base + j; v[j] = (idx < NN) ? cnt[idx] : 0; s += v[j]; }
    lds[t] = s; __syncthreads();
    for (int off = 1; off < 256; off <<= 1) {
        int add = (t >= off) ? lds[t - off] : 0;
        __syncthreads();
        lds[t] += add;
        __syncthreads();
    }
    int pre = partials[blockIdx.x] + lds[t] - s;  // exclusive prefix for this thread's 4
#pragma unroll
    for (int j = 0; j < 4; j++) {
        int idx = base + j;
        if (idx < NN) {
            rowstart[idx] = pre; cursor[idx] = pre; pre += v[j];
            deg[idx] = rsqrtf(deg[idx]);   // deg >= 1 always
        }
    }
}

__global__ void k_place(const int* __restrict__ ei, const float* __restrict__ ew,
                        int* __restrict__ cursor, int* __restrict__ srcs, float* __restrict__ wts) {
    int e = blockIdx.x * blockDim.x + threadIdx.x;
    if (e < NE) {
        int src = ei[e]; int dst = ei[NE + e]; float w = ew[e];
        int p = atomicAdd(&cursor[dst], 1);
        srcs[p] = src; wts[p] = w;
    }
}

// ---------------- hs = dinv * (x @ W1), stored bf16 ----------------
// block = 256 threads = 8 nodes x 32 features
__global__ __launch_bounds__(256) void k_hs(const float* __restrict__ x, const float* __restrict__ W1,
                                            const float* __restrict__ dinv, bf16* __restrict__ hs) {
    __shared__ float lw[IN_F * HID];  // 16 KB
    int t = threadIdx.x;
    for (int i = t; i < IN_F * HID; i += 256) lw[i] = W1[i];
    __syncthreads();
    int node = blockIdx.x * 8 + (t >> 5);  // NN % 8 == 0, no guard needed
    int f = t & 31;
    const float4* x4 = (const float4*)(x + (size_t)node * IN_F);
    float acc = 0.f;
#pragma unroll
    for (int k4 = 0; k4 < IN_F / 4; k4++) {
        float4 xv = x4[k4];
        int k = k4 * 4;
        acc += xv.x * lw[(k + 0) * HID + f];
        acc += xv.y * lw[(k + 1) * HID + f];
        acc += xv.z * lw[(k + 2) * HID + f];
        acc += xv.w * lw[(k + 3) * HID + f];
    }
    hs[(size_t)node * HID + f] = __float2bfloat16(dinv[node] * acc);
}

// ---------------- pull aggregation + epilogue ----------------
// block = 256 threads = 8 nodes x 32 lanes (lane = feature)
__global__ __launch_bounds__(256) void k_agg(const int* __restrict__ rowstart, const int* __restrict__ srcs,
                                             const float* __restrict__ wts, const bf16* __restrict__ hs,
                                             const float* __restrict__ dinv,
                                             const float* __restrict__ b1, const float* __restrict__ W2,
                                             const float* __restrict__ b2, float* __restrict__ out) {
    int t = threadIdx.x;
    int f = t & 31;
    int node = blockIdx.x * 8 + (t >> 5);
    int rs = rowstart[node], re = rowstart[node + 1];
    float acc = 0.f;
    for (int base = rs; base < re; base += 32) {
        int idx = base + f;
        int sreg = 0; float wreg = 0.f;
        if (idx < re) { sreg = srcs[idx]; wreg = wts[idx]; }
        int m = min(32, re - base);
        for (int j = 0; j < m; j++) {
            int s = __shfl(sreg, j, 32);
            float w = __shfl(wreg, j, 32);
            acc += w * __bfloat162float(hs[(size_t)s * HID + f]);
        }
    }
    float self = __bfloat162float(hs[(size_t)node * HID + f]);
    float v = dinv[node] * (self + acc) + b1[f];
    v = fmaxf(v, 0.f);
    float p = v * W2[f];
#pragma unroll
    for (int m = 16; m >= 1; m >>= 1) p += __shfl_xor(p, m, 32);
    if (f == 0) out[node] = p + b2[0];
}

// ---------------- launch ----------------

extern "C" void kernel_launch(void* const* d_in, const int* in_sizes, int n_in,
                              void* d_out, int out_size, void* d_ws, size_t ws_size,
                              hipStream_t stream) {
    const float* x  = (const float*)d_in[0];
    const int*   ei = (const int*)d_in[1];
    const float* ew = (const float*)d_in[2];
    const float* W1 = (const float*)d_in[3];
    const float* b1 = (const float*)d_in[4];
    const float* W2 = (const float*)d_in[5];
    const float* b2 = (const float*)d_in[6];
    float* out = (float*)d_out;

    char* ws = (char*)d_ws;
    // layout (16B-aligned offsets)
    float* deg      = (float*)(ws + 0);              // NN floats -> becomes dinv in place
    int*   cnt      = (int*)  (ws + 400000);         // NN ints
    int*   rowstart = (int*)  (ws + 800000);         // NN+1 ints
    int*   cursor   = (int*)  (ws + 1200128);        // NN ints
    int*   partials = (int*)  (ws + 1600128);        // 128 ints
    int*   srcs     = (int*)  (ws + 1600640);        // NE ints
    float* wts      = (float*)(ws + 14400640);       // NE floats
    bf16*  hs       = (bf16*) (ws + 27200640);       // NN*HID bf16
    // total ~33.6 MB

    const int NB_SCAN = (NN + 1023) / 1024;  // 98

    k_init<<<(NN + 255) / 256, 256, 0, stream>>>(deg, cnt);
    k_count<<<(NE + 255) / 256, 256, 0, stream>>>(ei, ew, deg, cnt);
    k_blocksum<<<NB_SCAN, 256, 0, stream>>>(cnt, partials);
    k_scanpartials<<<1, 64, 0, stream>>>(partials, NB_SCAN, rowstart);
    k_scatterscan<<<NB_SCAN, 256, 0, stream>>>(cnt, partials, rowstart, cursor, deg);
    k_hs<<<NN / 8, 256, 0, stream>>>(x, W1, deg /*dinv*/, hs);
    k_place<<<(NE + 255) / 256, 256, 0, stream>>>(ei, ew, cursor, srcs, wts);
    k_agg<<<NN / 8, 256, 0, stream>>>(rowstart, srcs, wts, hs, deg /*dinv*/, b1, W2, b2, out);
}